// Round 5
// baseline (617.664 us; speedup 1.0000x reference)
//
#include <hip/hip_runtime.h>
#include <stdint.h>

#define T_TOK 8192
#define HDIM  2048
#define NEXP  8
#define BM    128
#define BN    256
#define BK    32            // 4 chunks of 8 bf16 per row
#define RTOK  32            // tokens per router block

typedef __bf16 bf16x8 __attribute__((ext_vector_type(8)));
typedef float  f32x4  __attribute__((ext_vector_type(4)));
typedef unsigned short u16;
typedef u16    u16x8  __attribute__((ext_vector_type(8)));

typedef const __attribute__((address_space(1))) void* gptr_t;
typedef __attribute__((address_space(3))) void* lptr_t;

static __device__ __forceinline__ u16 f2bf(float f) {
    union { float f; unsigned u; } v; v.f = f;
    unsigned u = v.u;
    u = (u + 0x7FFFu + ((u >> 16) & 1u)) >> 16;   // RNE
    return (u16)u;
}

// fp32 -> bf16, 8 elems/thread (weights only; x is converted in router)
__global__ __launch_bounds__(256) void cvt_kernel(const float* __restrict__ in,
                                                  u16* __restrict__ out, int n8) {
    int i = blockIdx.x * 256 + threadIdx.x;
    if (i >= n8) return;
    const float4* p = (const float4*)in + (size_t)i * 2;
    float4 a = p[0], b = p[1];
    u16x8 r;
    r[0] = f2bf(a.x); r[1] = f2bf(a.y); r[2] = f2bf(a.z); r[3] = f2bf(a.w);
    r[4] = f2bf(b.x); r[5] = f2bf(b.y); r[6] = f2bf(b.z); r[7] = f2bf(b.w);
    ((u16x8*)out)[i] = r;
}

// Router: 32 tokens/block (4 waves x 8 tokens). Computes logits, top-2,
// converts x->bf16 on the fly, and scatters via per-block LDS lists +
// 8 global atomics per block.
__global__ __launch_bounds__(256) void router_kernel(const float* __restrict__ x,
                                                     const float* __restrict__ gw,
                                                     u16* __restrict__ xb,
                                                     float* __restrict__ logits_out,
                                                     int* __restrict__ cnt,
                                                     int* __restrict__ rows,
                                                     float* __restrict__ wts) {
    __shared__ int   lcnt[NEXP];
    __shared__ int   lbase[NEXP];
    __shared__ int   lrows[NEXP][RTOK];
    __shared__ float lwtsS[NEXP][RTOK];

    int tid  = threadIdx.x;
    int lane = tid & 63;
    int wave = tid >> 6;
    if (tid < NEXP) lcnt[tid] = 0;
    __syncthreads();

    int t0 = blockIdx.x * RTOK + wave * 8;
    const float4* g4 = (const float4*)gw;

    float acc[8][NEXP] = {};
    #pragma unroll
    for (int i = 0; i < HDIM / 4 / 64; i++) {      // 8 iters
        int idx = lane + i * 64;
        float4 gv[NEXP];
        #pragma unroll
        for (int e = 0; e < NEXP; e++) gv[e] = g4[e * (HDIM / 4) + idx];
        #pragma unroll
        for (int tk = 0; tk < 8; tk++) {
            int t = t0 + tk;
            float4 xv = ((const float4*)(x + (size_t)t * HDIM))[idx];
            ushort4 h;
            h.x = f2bf(xv.x); h.y = f2bf(xv.y); h.z = f2bf(xv.z); h.w = f2bf(xv.w);
            ((ushort4*)(xb + (size_t)t * HDIM))[idx] = h;
            #pragma unroll
            for (int e = 0; e < NEXP; e++)
                acc[tk][e] += xv.x * gv[e].x + xv.y * gv[e].y +
                              xv.z * gv[e].z + xv.w * gv[e].w;
        }
    }
    #pragma unroll
    for (int tk = 0; tk < 8; tk++)
        #pragma unroll
        for (int e = 0; e < NEXP; e++)
            #pragma unroll
            for (int off = 32; off > 0; off >>= 1)
                acc[tk][e] += __shfl_xor(acc[tk][e], off, 64);

    if (lane == 0) {
        #pragma unroll
        for (int tk = 0; tk < 8; tk++) {
            int t = t0 + tk;
            #pragma unroll
            for (int e = 0; e < NEXP; e++) logits_out[(size_t)t * NEXP + e] = acc[tk][e];
            int e0 = 0;
            #pragma unroll
            for (int e = 1; e < NEXP; e++) if (acc[tk][e] > acc[tk][e0]) e0 = e;
            int e1 = (e0 == 0) ? 1 : 0;
            #pragma unroll
            for (int e = 0; e < NEXP; e++)
                if (e != e0 && acc[tk][e] > acc[tk][e1]) e1 = e;
            float w0 = 1.0f / (1.0f + expf(acc[tk][e1] - acc[tk][e0]));
            int p0 = atomicAdd(&lcnt[e0], 1);
            lrows[e0][p0] = t; lwtsS[e0][p0] = w0;
            int p1 = atomicAdd(&lcnt[e1], 1);
            lrows[e1][p1] = t; lwtsS[e1][p1] = 1.0f - w0;
        }
    }
    __syncthreads();
    if (tid < NEXP) lbase[tid] = atomicAdd(&cnt[tid], lcnt[tid]);
    __syncthreads();
    int e = tid >> 5, j = tid & 31;                 // 8 experts x 32 slots
    if (j < lcnt[e]) {
        int b = lbase[e] + j;
        rows[e * T_TOK + b] = lrows[e][j];
        wts[e * T_TOK + b]  = lwtsS[e][j];
    }
}

// grouped GEMM, 128x256 tile, BK=32, 8 waves (2M x 4N, 64x64 out each),
// LDS 48 KB -> 2 blocks/CU co-resident (round-2's proven latency hider)
// AND 256-wide N (2.7x less VMEM staging than 128^2 — round-2's binder).
// Depth-2 counted-vmcnt pipeline (verified skeleton): top-of-tile wait
// vmcnt(3) = "my tile's 3 loads landed, next tile's 3 stay in flight";
// never drains to 0 in the loop. XCD swizzle: coltile == XCD, so each
// 1 MB B-panel lives in one XCD's L2 across its ~16 rowtile blocks.
__global__ __launch_bounds__(512, 4) void moe_gemm(const u16* __restrict__ xb,
                                                   const u16* __restrict__ wb,
                                                   const int* __restrict__ cnt,
                                                   const int* __restrict__ rows,
                                                   const float* __restrict__ wts,
                                                   float* __restrict__ out) {
    int p  = blockIdx.x;
    int xc = p & 7;                  // coltile (and XCD)
    int q  = p >> 3;
    int rt = q & 63;                 // rowtile 0..63
    int e  = q >> 6;                 // expert 0..7
    int nb = xc * BN;

    int count = cnt[e];
    int rowBase = rt * BM;
    if (rowBase >= count) return;

    const u16*   W     = wb  + (size_t)e * HDIM * HDIM;
    const int*   rlist = rows + e * T_TOK;
    const float* wlist = wts  + e * T_TOK;

    __shared__ u16 As[2][BM * BK];   // 2 x 8 KB
    __shared__ u16 Bs[2][BN * BK];   // 2 x 16 KB  -> 48 KB total

    int tid  = threadIdx.x;          // 0..511
    int lane = tid & 63;
    int wave = tid >> 6;             // 0..7
    int wr = wave >> 2, wc = wave & 3;
    int wslot = tid & ~63;           // wave-uniform

    // staging: slot s holds row s>>2, stored chunk s&3; logical chunk =
    // (s&3) ^ ((row>>1)&3). For both A (1 round, s=tid) and B (2 rounds,
    // s=l*512+tid) this reduces to clog = (tid&3)^((tid>>3)&3).
    int clog = ((tid & 3) ^ ((tid >> 3) & 3)) * 8;
    int arow = tid >> 2;                            // 0..127
    int atok = rlist[min(rowBase + arow, count - 1)];
    const u16* a_src = xb + (size_t)atok * HDIM + clog;
    const u16* b_src[2];
    #pragma unroll
    for (int l = 0; l < 2; l++)
        b_src[l] = W + (size_t)(nb + l * 128 + (tid >> 2)) * HDIM + clog;

    // 3 global_load_lds per thread per K-tile (1 A + 2 B) = 3 vmcnt slots
    auto stage = [&](int d, int kb) {
        __builtin_amdgcn_global_load_lds((gptr_t)(a_src + kb),
            (lptr_t)(&As[d][(size_t)tid * 8]), 16, 0, 0);
        #pragma unroll
        for (int l = 0; l < 2; l++)
            __builtin_amdgcn_global_load_lds((gptr_t)(b_src[l] + kb),
                (lptr_t)(&Bs[d][(size_t)(l * 512 + wslot + lane) * 8]), 16, 0, 0);
    };

    int lrow = lane & 15;
    int kq   = lane >> 4;            // chunk 0..3 (k = kq*8..kq*8+7)

    f32x4 acc[4][4] = {};

    auto compute = [&](const u16* A_lds, const u16* B_lds) {
        bf16x8 a[4], b[4];
        #pragma unroll
        for (int i = 0; i < 4; i++) {
            int r = wr * 64 + i * 16 + lrow;
            int aslot = (r << 2) | (kq ^ ((r >> 1) & 3));
            a[i] = *(const bf16x8*)(A_lds + (size_t)aslot * 8);
        }
        #pragma unroll
        for (int j = 0; j < 4; j++) {
            int c = wc * 64 + j * 16 + lrow;
            int bslot = (c << 2) | (kq ^ ((c >> 1) & 3));
            b[j] = *(const bf16x8*)(B_lds + (size_t)bslot * 8);
        }
        #pragma unroll
        for (int i = 0; i < 4; i++)
            #pragma unroll
            for (int j = 0; j < 4; j++)
                acc[i][j] = __builtin_amdgcn_mfma_f32_16x16x32_bf16(
                                a[i], b[j], acc[i][j], 0, 0, 0);
    };

    // ---- depth-2 counted-vmcnt pipeline over 64 K-tiles ----
    stage(0, 0);
    stage(1, BK);

    // tiles 0..61 (31 iters x 2); stages reach tile 63 (kb max 2016 < 2048)
    for (int kb = 0; kb < HDIM - 2 * BK; kb += 2 * BK) {
        asm volatile("s_waitcnt vmcnt(3)" ::: "memory");
        __builtin_amdgcn_sched_barrier(0);
        __builtin_amdgcn_s_barrier();              // tile t landed for all
        compute(As[0], Bs[0]);
        __builtin_amdgcn_sched_barrier(0);
        __builtin_amdgcn_s_barrier();              // all waves done with buf0
        stage(0, kb + 2 * BK);

        asm volatile("s_waitcnt vmcnt(3)" ::: "memory");
        __builtin_amdgcn_sched_barrier(0);
        __builtin_amdgcn_s_barrier();
        compute(As[1], Bs[1]);
        __builtin_amdgcn_sched_barrier(0);
        __builtin_amdgcn_s_barrier();              // all waves done with buf1
        stage(1, kb + 3 * BK);
    }
    // tile 62
    asm volatile("s_waitcnt vmcnt(3)" ::: "memory");
    __builtin_amdgcn_sched_barrier(0);
    __builtin_amdgcn_s_barrier();
    compute(As[0], Bs[0]);
    // tile 63 (drain)
    asm volatile("s_waitcnt vmcnt(0)" ::: "memory");
    __builtin_amdgcn_sched_barrier(0);
    __builtin_amdgcn_s_barrier();
    compute(As[1], Bs[1]);

    int srow = (lane >> 4) * 4;
    #pragma unroll
    for (int i = 0; i < 4; i++) {
        #pragma unroll
        for (int r = 0; r < 4; r++) {
            int row = rowBase + wr * 64 + i * 16 + srow + r;
            if (row < count) {
                int   tok = rlist[row];
                float wgt = wlist[row];
                #pragma unroll
                for (int j = 0; j < 4; j++) {
                    int col = nb + wc * 64 + j * 16 + lrow;
                    atomicAdd(out + (size_t)tok * HDIM + col, wgt * acc[i][j][r]);
                }
            }
        }
    }
}

extern "C" void kernel_launch(void* const* d_in, const int* in_sizes, int n_in,
                              void* d_out, int out_size, void* d_ws, size_t ws_size,
                              hipStream_t stream) {
    const float* x  = (const float*)d_in[0];   // [T, H]
    const float* gw = (const float*)d_in[1];   // [E, H]
    const float* ew = (const float*)d_in[2];   // [E, H, H]
    float* out    = (float*)d_out;             // [T, H] fp32
    float* logits = out + (size_t)T_TOK * HDIM;

    char* ws = (char*)d_ws;
    int*   cnt  = (int*)ws;                                   // 32 B
    int*   rows = (int*)(ws + 1024);                          // 256 KB
    float* wts  = (float*)(ws + 1024 + 262144);               // 256 KB
    u16*   xb   = (u16*)(ws + 1024 + 2 * 262144);             // 32 MB
    u16*   wb   = xb + (size_t)T_TOK * HDIM;                  // 64 MB

    hipMemsetAsync(d_out, 0, (size_t)T_TOK * HDIM * sizeof(float), stream);
    hipMemsetAsync(cnt, 0, NEXP * sizeof(int), stream);

    int nw8 = NEXP * HDIM * HDIM / 8;
    cvt_kernel<<<(nw8 + 255) / 256, 256, 0, stream>>>(ew, wb, nw8);

    router_kernel<<<T_TOK / RTOK, 256, 0, stream>>>(x, gw, xb, logits, cnt, rows, wts);

    moe_gemm<<<NEXP * 64 * 8, 512, 0, stream>>>(xb, wb, cnt, rows, wts, out);
}

// Round 7
// 560.869 us; speedup vs baseline: 1.1013x; 1.1013x over previous
//
#include <hip/hip_runtime.h>
#include <stdint.h>

#define T_TOK 8192
#define HDIM  2048
#define NEXP  8
#define TILE  128
#define BK    64            // k-elems per LDS tile; 8 chunks of 8 bf16 per row
#define RTOK  32            // tokens per router block

typedef __bf16 bf16x8 __attribute__((ext_vector_type(8)));
typedef float  f32x4  __attribute__((ext_vector_type(4)));
typedef unsigned short u16;
typedef u16    u16x8  __attribute__((ext_vector_type(8)));

typedef const __attribute__((address_space(1))) void* gptr_t;
typedef __attribute__((address_space(3))) void* lptr_t;

static __device__ __forceinline__ u16 f2bf(float f) {
    union { float f; unsigned u; } v; v.f = f;
    unsigned u = v.u;
    u = (u + 0x7FFFu + ((u >> 16) & 1u)) >> 16;   // RNE
    return (u16)u;
}

// fp32 -> bf16, 8 elems/thread (weights only; x is converted in router)
__global__ __launch_bounds__(256) void cvt_kernel(const float* __restrict__ in,
                                                  u16* __restrict__ out, int n8) {
    int i = blockIdx.x * 256 + threadIdx.x;
    if (i >= n8) return;
    const float4* p = (const float4*)in + (size_t)i * 2;
    float4 a = p[0], b = p[1];
    u16x8 r;
    r[0] = f2bf(a.x); r[1] = f2bf(a.y); r[2] = f2bf(a.z); r[3] = f2bf(a.w);
    r[4] = f2bf(b.x); r[5] = f2bf(b.y); r[6] = f2bf(b.z); r[7] = f2bf(b.w);
    ((u16x8*)out)[i] = r;
}

// Router: 32 tokens/block (4 waves x 8 tokens). Computes logits, top-2,
// converts x->bf16 on the fly. Scatter lists store PACKED slot ids
// (tok*2 + k, k=0 for top-1 expert, k=1 for top-2) so the GEMM can write
// its output row straight to cbuf[tok*2+k] and the combine is contiguous.
__global__ __launch_bounds__(256) void router_kernel(const float* __restrict__ x,
                                                     const float* __restrict__ gw,
                                                     u16* __restrict__ xb,
                                                     float* __restrict__ logits_out,
                                                     int* __restrict__ cnt,
                                                     int* __restrict__ rows,
                                                     float* __restrict__ wts) {
    __shared__ int   lcnt[NEXP];
    __shared__ int   lbase[NEXP];
    __shared__ int   lrows[NEXP][RTOK];
    __shared__ float lwtsS[NEXP][RTOK];

    int tid  = threadIdx.x;
    int lane = tid & 63;
    int wave = tid >> 6;
    if (tid < NEXP) lcnt[tid] = 0;
    __syncthreads();

    int t0 = blockIdx.x * RTOK + wave * 8;
    const float4* g4 = (const float4*)gw;

    float acc[8][NEXP] = {};
    #pragma unroll
    for (int i = 0; i < HDIM / 4 / 64; i++) {      // 8 iters
        int idx = lane + i * 64;
        float4 gv[NEXP];
        #pragma unroll
        for (int e = 0; e < NEXP; e++) gv[e] = g4[e * (HDIM / 4) + idx];
        #pragma unroll
        for (int tk = 0; tk < 8; tk++) {
            int t = t0 + tk;
            float4 xv = ((const float4*)(x + (size_t)t * HDIM))[idx];
            ushort4 h;
            h.x = f2bf(xv.x); h.y = f2bf(xv.y); h.z = f2bf(xv.z); h.w = f2bf(xv.w);
            ((ushort4*)(xb + (size_t)t * HDIM))[idx] = h;
            #pragma unroll
            for (int e = 0; e < NEXP; e++)
                acc[tk][e] += xv.x * gv[e].x + xv.y * gv[e].y +
                              xv.z * gv[e].z + xv.w * gv[e].w;
        }
    }
    #pragma unroll
    for (int tk = 0; tk < 8; tk++)
        #pragma unroll
        for (int e = 0; e < NEXP; e++)
            #pragma unroll
            for (int off = 32; off > 0; off >>= 1)
                acc[tk][e] += __shfl_xor(acc[tk][e], off, 64);

    if (lane == 0) {
        #pragma unroll
        for (int tk = 0; tk < 8; tk++) {
            int t = t0 + tk;
            #pragma unroll
            for (int e = 0; e < NEXP; e++) logits_out[(size_t)t * NEXP + e] = acc[tk][e];
            int e0 = 0;
            #pragma unroll
            for (int e = 1; e < NEXP; e++) if (acc[tk][e] > acc[tk][e0]) e0 = e;
            int e1 = (e0 == 0) ? 1 : 0;
            #pragma unroll
            for (int e = 0; e < NEXP; e++)
                if (e != e0 && acc[tk][e] > acc[tk][e1]) e1 = e;
            float w0 = 1.0f / (1.0f + expf(acc[tk][e1] - acc[tk][e0]));
            int p0 = atomicAdd(&lcnt[e0], 1);
            lrows[e0][p0] = t * 2;     lwtsS[e0][p0] = w0;        // slot k=0
            int p1 = atomicAdd(&lcnt[e1], 1);
            lrows[e1][p1] = t * 2 + 1; lwtsS[e1][p1] = 1.0f - w0; // slot k=1
        }
    }
    __syncthreads();
    if (tid < NEXP) lbase[tid] = atomicAdd(&cnt[tid], lcnt[tid]);
    __syncthreads();
    int e = tid >> 5, j = tid & 31;                 // 8 experts x 32 slots
    if (j < lcnt[e]) {
        int b = lbase[e] + j;
        rows[e * T_TOK + b] = lrows[e][j];
        wts[e * T_TOK + b]  = lwtsS[e][j];
    }
}

// grouped GEMM, m97 tile + XCD swizzle + depth-2 counted-vmcnt pipeline
// (round-2 verified structure, best measured). Epilogue: ATOMIC-FREE —
// pre-weighted row stored as bf16 to cbuf[tok*2+k] with plain stores
// (no RMW, no indirection beyond the rlist entry itself).
__global__ __launch_bounds__(256) void moe_gemm(const u16* __restrict__ xb,
                                                const u16* __restrict__ wb,
                                                const int* __restrict__ cnt,
                                                const int* __restrict__ rows,
                                                const float* __restrict__ wts,
                                                u16* __restrict__ cbuf) {
    int p  = blockIdx.x;
    int xc = p & 7;
    int q  = p >> 3;
    int rt = q & 63;
    int g  = (q >> 6) * 8 + xc;      // 0..127 = expert*16 + coltile
    int e  = g >> 4;
    int nb = (g & 15) * TILE;

    int count = cnt[e];
    int rowBase = rt * TILE;
    if (rowBase >= count) return;

    const u16*   W     = wb  + (size_t)e * HDIM * HDIM;
    const int*   rlist = rows + e * T_TOK;
    const float* wlist = wts  + e * T_TOK;

    __shared__ u16 As[2][TILE * BK];   // 2 x 16 KB
    __shared__ u16 Bs[2][TILE * BK];   // 2 x 16 KB  -> 64 KB total

    int tid  = threadIdx.x;
    int lane = tid & 63;
    int wave = tid >> 6;
    int wr = wave >> 1, wc = wave & 1;

    // staging: thread tid stages slot (pp*256 + tid); row = slot>>3,
    // stored chunk = slot&7, logical chunk = (slot&7)^(row&7)
    const u16* a_src[4];
    const u16* b_src[4];
    #pragma unroll
    for (int pp = 0; pp < 4; pp++) {
        int row  = (tid >> 3) + pp * 32;            // 0..127
        int clog = (tid & 7) ^ (row & 7);
        int tok  = rlist[min(rowBase + row, count - 1)] >> 1;   // decode packed slot
        a_src[pp] = xb + (size_t)tok * HDIM + clog * 8;
        b_src[pp] = W + (size_t)(nb + row) * HDIM + clog * 8;
    }
    int wslot = (tid & ~63);                        // wave-uniform

    // 8 global_load_lds per thread per K-tile = 8 vmcnt slots
    auto stage = [&](u16* A_lds, u16* B_lds, int kb) {
        #pragma unroll
        for (int pp = 0; pp < 4; pp++) {
            __builtin_amdgcn_global_load_lds((gptr_t)(a_src[pp] + kb),
                                             (lptr_t)(A_lds + (pp * 256 + wslot) * 8),
                                             16, 0, 0);
            __builtin_amdgcn_global_load_lds((gptr_t)(b_src[pp] + kb),
                                             (lptr_t)(B_lds + (pp * 256 + wslot) * 8),
                                             16, 0, 0);
        }
    };

    int lrow = lane & 15;
    int kq   = lane >> 4;
    int mloc[4], nloc[4];
    #pragma unroll
    for (int i = 0; i < 4; i++) {
        mloc[i] = wr * 64 + i * 16 + lrow;
        nloc[i] = wc * 64 + i * 16 + lrow;
    }

    f32x4 acc[4][4] = {};

    auto compute = [&](const u16* A_lds, const u16* B_lds) {
        #pragma unroll
        for (int s = 0; s < 2; s++) {
            int chunk = s * 4 + kq;
            bf16x8 a[4], b[4];
            #pragma unroll
            for (int i = 0; i < 4; i++) {
                int aslot = (mloc[i] << 3) | (chunk ^ (mloc[i] & 7));
                int bslot = (nloc[i] << 3) | (chunk ^ (nloc[i] & 7));
                a[i] = *(const bf16x8*)(A_lds + aslot * 8);   // (param, not As!)
                b[i] = *(const bf16x8*)(B_lds + bslot * 8);
            }
            #pragma unroll
            for (int mt = 0; mt < 4; mt++)
                #pragma unroll
                for (int nt = 0; nt < 4; nt++)
                    acc[mt][nt] = __builtin_amdgcn_mfma_f32_16x16x32_bf16(
                                      a[mt], b[nt], acc[mt][nt], 0, 0, 0);
        }
    };

    // ---- depth-2 counted-vmcnt pipeline over 32 K-tiles ----
    stage(As[0], Bs[0], 0);
    stage(As[1], Bs[1], BK);

    for (int kb = 0; kb < HDIM - 2 * BK; kb += 2 * BK) {
        asm volatile("s_waitcnt vmcnt(8)" ::: "memory");
        __builtin_amdgcn_sched_barrier(0);
        __builtin_amdgcn_s_barrier();              // tile t data visible to all
        compute(As[0], Bs[0]);
        __builtin_amdgcn_sched_barrier(0);
        __builtin_amdgcn_s_barrier();              // all waves done reading buf0
        stage(As[0], Bs[0], kb + 2 * BK);

        asm volatile("s_waitcnt vmcnt(8)" ::: "memory");
        __builtin_amdgcn_sched_barrier(0);
        __builtin_amdgcn_s_barrier();
        compute(As[1], Bs[1]);
        __builtin_amdgcn_sched_barrier(0);
        __builtin_amdgcn_s_barrier();              // all waves done reading buf1
        stage(As[1], Bs[1], kb + 3 * BK);
    }
    // tile 30
    asm volatile("s_waitcnt vmcnt(8)" ::: "memory");
    __builtin_amdgcn_sched_barrier(0);
    __builtin_amdgcn_s_barrier();
    compute(As[0], Bs[0]);
    // tile 31 (drain)
    asm volatile("s_waitcnt vmcnt(0)" ::: "memory");
    __builtin_amdgcn_sched_barrier(0);
    __builtin_amdgcn_s_barrier();
    compute(As[1], Bs[1]);

    int srow = (lane >> 4) * 4;
    #pragma unroll
    for (int mt = 0; mt < 4; mt++) {
        #pragma unroll
        for (int r = 0; r < 4; r++) {
            int row = rowBase + wr * 64 + mt * 16 + srow + r;
            if (row < count) {
                int   slot = rlist[row];            // tok*2 + k
                float wgt  = wlist[row];
                u16* crow = cbuf + (size_t)slot * HDIM;
                #pragma unroll
                for (int nt = 0; nt < 4; nt++) {
                    int col = nb + wc * 64 + nt * 16 + lrow;
                    crow[col] = f2bf(wgt * acc[mt][nt][r]);   // plain store
                }
            }
        }
    }
}

// combine: out[t] = cbuf[2t] + cbuf[2t+1]  (weights pre-applied in gemm)
__global__ __launch_bounds__(256) void combine_kernel(const u16* __restrict__ cbuf,
                                                      float* __restrict__ out) {
    int t  = blockIdx.x;
    int c8 = threadIdx.x;                           // 2048/8 = 256 chunks
    u16x8 a = ((const u16x8*)(cbuf + (size_t)(t * 2)     * HDIM))[c8];
    u16x8 b = ((const u16x8*)(cbuf + (size_t)(t * 2 + 1) * HDIM))[c8];
    float4 o[2];
    #pragma unroll
    for (int j = 0; j < 8; j++) {
        union { unsigned u; float f; } va, vb;
        va.u = (unsigned)a[j] << 16;
        vb.u = (unsigned)b[j] << 16;
        ((float*)o)[j] = va.f + vb.f;
    }
    float4* op = (float4*)(out + (size_t)t * HDIM + c8 * 8);
    op[0] = o[0];
    op[1] = o[1];
}

extern "C" void kernel_launch(void* const* d_in, const int* in_sizes, int n_in,
                              void* d_out, int out_size, void* d_ws, size_t ws_size,
                              hipStream_t stream) {
    const float* x  = (const float*)d_in[0];   // [T, H]
    const float* gw = (const float*)d_in[1];   // [E, H]
    const float* ew = (const float*)d_in[2];   // [E, H, H]
    float* out    = (float*)d_out;             // [T, H] fp32
    float* logits = out + (size_t)T_TOK * HDIM;

    char* ws = (char*)d_ws;
    int*   cnt  = (int*)ws;                                   // 32 B
    int*   rows = (int*)(ws + 1024);                          // 256 KB
    float* wts  = (float*)(ws + 1024 + 262144);               // 256 KB
    u16*   xb   = (u16*)(ws + 1024 + 2 * 262144);             // 32 MB
    u16*   wb   = xb + (size_t)T_TOK * HDIM;                  // 64 MB
    u16*   cbuf = wb + (size_t)NEXP * HDIM * HDIM;            // 64 MB (2T x H bf16)

    hipMemsetAsync(cnt, 0, NEXP * sizeof(int), stream);
    // no output memset needed: combine fully overwrites out, router logits.

    int nw8 = NEXP * HDIM * HDIM / 8;
    cvt_kernel<<<(nw8 + 255) / 256, 256, 0, stream>>>(ew, wb, nw8);

    router_kernel<<<T_TOK / RTOK, 256, 0, stream>>>(x, gw, xb, logits, cnt, rows, wts);

    moe_gemm<<<NEXP * 64 * 16, 256, 0, stream>>>(xb, wb, cnt, rows, wts, cbuf);

    combine_kernel<<<T_TOK, 256, 0, stream>>>(cbuf, out);
}

// Round 8
// 522.284 us; speedup vs baseline: 1.1826x; 1.0739x over previous
//
#include <hip/hip_runtime.h>
#include <stdint.h>

#define T_TOK 8192
#define HDIM  2048
#define NEXP  8
#define TILE  128
#define BK    64            // k-elems per LDS tile; 8 chunks of 8 bf16 per row
#define RTOK  32            // tokens per router block
#define NRBLK (T_TOK / RTOK)   // 256 router blocks

typedef __bf16 bf16x8 __attribute__((ext_vector_type(8)));
typedef float  f32x4  __attribute__((ext_vector_type(4)));
typedef unsigned short u16;
typedef u16    u16x8  __attribute__((ext_vector_type(8)));

typedef const __attribute__((address_space(1))) void* gptr_t;
typedef __attribute__((address_space(3))) void* lptr_t;

static __device__ __forceinline__ u16 f2bf(float f) {
    union { float f; unsigned u; } v; v.f = f;
    unsigned u = v.u;
    u = (u + 0x7FFFu + ((u >> 16) & 1u)) >> 16;   // RNE
    return (u16)u;
}

// Fused producer kernel: blocks 0..NRBLK-1 run the router (top-2 + x->bf16
// + packed-slot scatter lists); blocks NRBLK.. run the weight fp32->bf16
// convert. Independent work fused so both memory-bound phases overlap.
__global__ __launch_bounds__(256) void cvt_router_kernel(const float* __restrict__ x,
                                                         const float* __restrict__ gw,
                                                         const float* __restrict__ ew,
                                                         u16* __restrict__ xb,
                                                         u16* __restrict__ wb,
                                                         float* __restrict__ logits_out,
                                                         int* __restrict__ cnt,
                                                         int* __restrict__ rows,
                                                         float* __restrict__ wts) {
    __shared__ int   lcnt[NEXP];
    __shared__ int   lbase[NEXP];
    __shared__ int   lrows[NEXP][RTOK];
    __shared__ float lwtsS[NEXP][RTOK];

    int tid = threadIdx.x;

    if (blockIdx.x >= NRBLK) {
        // ---- weight convert path: 8 fp32 -> 8 bf16 per thread ----
        int i = (blockIdx.x - NRBLK) * 256 + tid;   // < NEXP*HDIM*HDIM/8
        const float4* p = (const float4*)ew + (size_t)i * 2;
        float4 a = p[0], b = p[1];
        u16x8 r;
        r[0] = f2bf(a.x); r[1] = f2bf(a.y); r[2] = f2bf(a.z); r[3] = f2bf(a.w);
        r[4] = f2bf(b.x); r[5] = f2bf(b.y); r[6] = f2bf(b.z); r[7] = f2bf(b.w);
        ((u16x8*)wb)[i] = r;
        return;
    }

    // ---- router path ----
    int lane = tid & 63;
    int wave = tid >> 6;
    if (tid < NEXP) lcnt[tid] = 0;
    __syncthreads();

    int t0 = blockIdx.x * RTOK + wave * 8;
    const float4* g4 = (const float4*)gw;

    float acc[8][NEXP] = {};
    #pragma unroll
    for (int i = 0; i < HDIM / 4 / 64; i++) {      // 8 iters
        int idx = lane + i * 64;
        float4 gv[NEXP];
        #pragma unroll
        for (int e = 0; e < NEXP; e++) gv[e] = g4[e * (HDIM / 4) + idx];
        #pragma unroll
        for (int tk = 0; tk < 8; tk++) {
            int t = t0 + tk;
            float4 xv = ((const float4*)(x + (size_t)t * HDIM))[idx];
            ushort4 h;
            h.x = f2bf(xv.x); h.y = f2bf(xv.y); h.z = f2bf(xv.z); h.w = f2bf(xv.w);
            ((ushort4*)(xb + (size_t)t * HDIM))[idx] = h;
            #pragma unroll
            for (int e = 0; e < NEXP; e++)
                acc[tk][e] += xv.x * gv[e].x + xv.y * gv[e].y +
                              xv.z * gv[e].z + xv.w * gv[e].w;
        }
    }
    #pragma unroll
    for (int tk = 0; tk < 8; tk++)
        #pragma unroll
        for (int e = 0; e < NEXP; e++)
            #pragma unroll
            for (int off = 32; off > 0; off >>= 1)
                acc[tk][e] += __shfl_xor(acc[tk][e], off, 64);

    if (lane == 0) {
        #pragma unroll
        for (int tk = 0; tk < 8; tk++) {
            int t = t0 + tk;
            #pragma unroll
            for (int e = 0; e < NEXP; e++) logits_out[(size_t)t * NEXP + e] = acc[tk][e];
            int e0 = 0;
            #pragma unroll
            for (int e = 1; e < NEXP; e++) if (acc[tk][e] > acc[tk][e0]) e0 = e;
            int e1 = (e0 == 0) ? 1 : 0;
            #pragma unroll
            for (int e = 0; e < NEXP; e++)
                if (e != e0 && acc[tk][e] > acc[tk][e1]) e1 = e;
            float w0 = 1.0f / (1.0f + expf(acc[tk][e1] - acc[tk][e0]));
            int p0 = atomicAdd(&lcnt[e0], 1);
            lrows[e0][p0] = t * 2;     lwtsS[e0][p0] = w0;        // slot k=0
            int p1 = atomicAdd(&lcnt[e1], 1);
            lrows[e1][p1] = t * 2 + 1; lwtsS[e1][p1] = 1.0f - w0; // slot k=1
        }
    }
    __syncthreads();
    if (tid < NEXP) lbase[tid] = atomicAdd(&cnt[tid], lcnt[tid]);
    __syncthreads();
    int e = tid >> 5, j = tid & 31;                 // 8 experts x 32 slots
    if (j < lcnt[e]) {
        int b = lbase[e] + j;
        rows[e * T_TOK + b] = lrows[e][j];
        wts[e * T_TOK + b]  = lwtsS[e][j];
    }
}

// grouped GEMM, m97 tile + depth-2 counted-vmcnt pipeline (round-7
// verified structure). XCD swizzle keyed by EXPERT: p&7 == e -> all of
// expert e's blocks on one XCD, so A rows AND W panels K-slabs stay in
// that XCD's L2 (resident set shares one expert; consecutive local ids
// share a rowtile and span the 16 coltiles -> ~340 KB working stripe).
// Epilogue: atomic-free bf16 stores to cbuf[tok*2+k].
__global__ __launch_bounds__(256) void moe_gemm(const u16* __restrict__ xb,
                                                const u16* __restrict__ wb,
                                                const int* __restrict__ cnt,
                                                const int* __restrict__ rows,
                                                const float* __restrict__ wts,
                                                u16* __restrict__ cbuf) {
    int p     = blockIdx.x;
    int e     = p & 7;               // expert == XCD
    int local = p >> 3;              // 0..1023
    int rt    = local >> 4;          // rowtile 0..63
    int nb    = (local & 15) * TILE; // coltile

    int count = cnt[e];
    int rowBase = rt * TILE;
    if (rowBase >= count) return;

    const u16*   W     = wb  + (size_t)e * HDIM * HDIM;
    const int*   rlist = rows + e * T_TOK;
    const float* wlist = wts  + e * T_TOK;

    __shared__ u16 As[2][TILE * BK];   // 2 x 16 KB
    __shared__ u16 Bs[2][TILE * BK];   // 2 x 16 KB  -> 64 KB total

    int tid  = threadIdx.x;
    int lane = tid & 63;
    int wave = tid >> 6;
    int wr = wave >> 1, wc = wave & 1;

    // staging: thread tid stages slot (pp*256 + tid); row = slot>>3,
    // stored chunk = slot&7, logical chunk = (slot&7)^(row&7)
    const u16* a_src[4];
    const u16* b_src[4];
    #pragma unroll
    for (int pp = 0; pp < 4; pp++) {
        int row  = (tid >> 3) + pp * 32;            // 0..127
        int clog = (tid & 7) ^ (row & 7);
        int tok  = rlist[min(rowBase + row, count - 1)] >> 1;   // decode packed slot
        a_src[pp] = xb + (size_t)tok * HDIM + clog * 8;
        b_src[pp] = W + (size_t)(nb + row) * HDIM + clog * 8;
    }
    int wslot = (tid & ~63);                        // wave-uniform

    // 8 global_load_lds per thread per K-tile = 8 vmcnt slots
    auto stage = [&](u16* A_lds, u16* B_lds, int kb) {
        #pragma unroll
        for (int pp = 0; pp < 4; pp++) {
            __builtin_amdgcn_global_load_lds((gptr_t)(a_src[pp] + kb),
                                             (lptr_t)(A_lds + (pp * 256 + wslot) * 8),
                                             16, 0, 0);
            __builtin_amdgcn_global_load_lds((gptr_t)(b_src[pp] + kb),
                                             (lptr_t)(B_lds + (pp * 256 + wslot) * 8),
                                             16, 0, 0);
        }
    };

    int lrow = lane & 15;
    int kq   = lane >> 4;
    int mloc[4], nloc[4];
    #pragma unroll
    for (int i = 0; i < 4; i++) {
        mloc[i] = wr * 64 + i * 16 + lrow;
        nloc[i] = wc * 64 + i * 16 + lrow;
    }

    f32x4 acc[4][4] = {};

    auto compute = [&](const u16* A_lds, const u16* B_lds) {
        #pragma unroll
        for (int s = 0; s < 2; s++) {
            int chunk = s * 4 + kq;
            bf16x8 a[4], b[4];
            #pragma unroll
            for (int i = 0; i < 4; i++) {
                int aslot = (mloc[i] << 3) | (chunk ^ (mloc[i] & 7));
                int bslot = (nloc[i] << 3) | (chunk ^ (nloc[i] & 7));
                a[i] = *(const bf16x8*)(A_lds + aslot * 8);
                b[i] = *(const bf16x8*)(B_lds + bslot * 8);
            }
            #pragma unroll
            for (int mt = 0; mt < 4; mt++)
                #pragma unroll
                for (int nt = 0; nt < 4; nt++)
                    acc[mt][nt] = __builtin_amdgcn_mfma_f32_16x16x32_bf16(
                                      a[mt], b[nt], acc[mt][nt], 0, 0, 0);
        }
    };

    // ---- depth-2 counted-vmcnt pipeline over 32 K-tiles ----
    stage(As[0], Bs[0], 0);
    stage(As[1], Bs[1], BK);

    for (int kb = 0; kb < HDIM - 2 * BK; kb += 2 * BK) {
        asm volatile("s_waitcnt vmcnt(8)" ::: "memory");
        __builtin_amdgcn_sched_barrier(0);
        __builtin_amdgcn_s_barrier();              // tile t data visible to all
        compute(As[0], Bs[0]);
        __builtin_amdgcn_sched_barrier(0);
        __builtin_amdgcn_s_barrier();              // all waves done reading buf0
        stage(As[0], Bs[0], kb + 2 * BK);

        asm volatile("s_waitcnt vmcnt(8)" ::: "memory");
        __builtin_amdgcn_sched_barrier(0);
        __builtin_amdgcn_s_barrier();
        compute(As[1], Bs[1]);
        __builtin_amdgcn_sched_barrier(0);
        __builtin_amdgcn_s_barrier();              // all waves done reading buf1
        stage(As[1], Bs[1], kb + 3 * BK);
    }
    // tile 30
    asm volatile("s_waitcnt vmcnt(8)" ::: "memory");
    __builtin_amdgcn_sched_barrier(0);
    __builtin_amdgcn_s_barrier();
    compute(As[0], Bs[0]);
    // tile 31 (drain)
    asm volatile("s_waitcnt vmcnt(0)" ::: "memory");
    __builtin_amdgcn_sched_barrier(0);
    __builtin_amdgcn_s_barrier();
    compute(As[1], Bs[1]);

    int srow = (lane >> 4) * 4;
    #pragma unroll
    for (int mt = 0; mt < 4; mt++) {
        #pragma unroll
        for (int r = 0; r < 4; r++) {
            int row = rowBase + wr * 64 + mt * 16 + srow + r;
            if (row < count) {
                int   slot = rlist[row];            // tok*2 + k
                float wgt  = wlist[row];
                u16* crow = cbuf + (size_t)slot * HDIM;
                #pragma unroll
                for (int nt = 0; nt < 4; nt++) {
                    int col = nb + wc * 64 + nt * 16 + lrow;
                    crow[col] = f2bf(wgt * acc[mt][nt][r]);   // plain store
                }
            }
        }
    }
}

// combine: out[t] = cbuf[2t] + cbuf[2t+1]  (weights pre-applied in gemm)
__global__ __launch_bounds__(256) void combine_kernel(const u16* __restrict__ cbuf,
                                                      float* __restrict__ out) {
    int t  = blockIdx.x;
    int c8 = threadIdx.x;                           // 2048/8 = 256 chunks
    u16x8 a = ((const u16x8*)(cbuf + (size_t)(t * 2)     * HDIM))[c8];
    u16x8 b = ((const u16x8*)(cbuf + (size_t)(t * 2 + 1) * HDIM))[c8];
    float4 o[2];
    #pragma unroll
    for (int j = 0; j < 8; j++) {
        union { unsigned u; float f; } va, vb;
        va.u = (unsigned)a[j] << 16;
        vb.u = (unsigned)b[j] << 16;
        ((float*)o)[j] = va.f + vb.f;
    }
    float4* op = (float4*)(out + (size_t)t * HDIM + c8 * 8);
    op[0] = o[0];
    op[1] = o[1];
}

extern "C" void kernel_launch(void* const* d_in, const int* in_sizes, int n_in,
                              void* d_out, int out_size, void* d_ws, size_t ws_size,
                              hipStream_t stream) {
    const float* x  = (const float*)d_in[0];   // [T, H]
    const float* gw = (const float*)d_in[1];   // [E, H]
    const float* ew = (const float*)d_in[2];   // [E, H, H]
    float* out    = (float*)d_out;             // [T, H] fp32
    float* logits = out + (size_t)T_TOK * HDIM;

    char* ws = (char*)d_ws;
    int*   cnt  = (int*)ws;                                   // 32 B
    int*   rows = (int*)(ws + 1024);                          // 256 KB
    float* wts  = (float*)(ws + 1024 + 262144);               // 256 KB
    u16*   xb   = (u16*)(ws + 1024 + 2 * 262144);             // 32 MB
    u16*   wb   = xb + (size_t)T_TOK * HDIM;                  // 64 MB
    u16*   cbuf = wb + (size_t)NEXP * HDIM * HDIM;            // 64 MB (2T x H bf16)

    hipMemsetAsync(cnt, 0, NEXP * sizeof(int), stream);
    // no output memset needed: combine fully overwrites out, router logits.

    int nw8 = NEXP * HDIM * HDIM / 8;                         // 4M chunks
    int ncvt = nw8 / 256;                                     // 16384 blocks
    cvt_router_kernel<<<NRBLK + ncvt, 256, 0, stream>>>(x, gw, ew, xb, wb,
                                                        logits, cnt, rows, wts);

    moe_gemm<<<NEXP * 64 * 16, 256, 0, stream>>>(xb, wb, cnt, rows, wts, cbuf);

    combine_kernel<<<T_TOK, 256, 0, stream>>>(cbuf, out);
}